// Round 3
// baseline (930.863 us; speedup 1.0000x reference)
//
#include <hip/hip_runtime.h>
#include <hip/hip_bf16.h>

typedef __attribute__((ext_vector_type(8))) short   bf16x8;
typedef __attribute__((ext_vector_type(4))) float   f32x4;
typedef __attribute__((ext_vector_type(4))) unsigned short u16x4;
typedef unsigned short u16;

#define NTOK 64
#define CEMB 192
#define NH   6
#define ROWB 384   // row bytes for [64][192] bf16 tiles
#define VROWB 128  // row bytes for vhT [192][64] bf16
#define WPB  4     // windows per block (grid 512, fully resident at 2 blocks/CU)

__device__ __forceinline__ u16 f2b(float f) {
  unsigned u = __float_as_uint(f);
  unsigned r = (u + 0x7fffu + ((u >> 16) & 1u)) >> 16;  // RNE
  return (u16)r;
}

__device__ __forceinline__ int swz(int row, int colbyte) {
  return colbyte ^ ((((row >> 3) ^ row) & 7) << 4);
}

// ---------------- prep: pack W^T (bf16) + gather rel_bias ----------------
__global__ void prep_kernel(const float* __restrict__ Wq, const float* __restrict__ Wk,
                            const float* __restrict__ Wv, const float* __restrict__ Wp,
                            const float* __restrict__ btab, const int* __restrict__ ridx,
                            u16* __restrict__ WT, float* __restrict__ rb) {
  int idx = blockIdx.x * 256 + threadIdx.x;
  if (idx < 4 * 36864) {
    int m = idx / 36864;
    int e = idx - m * 36864;
    int n = e / CEMB;
    int k = e - n * CEMB;
    const float* W = (m == 0) ? Wq : (m == 1) ? Wk : (m == 2) ? Wv : Wp;
    WT[idx] = f2b(W[k * CEMB + n]);          // WT[m][n][k] = W[k][n]
  } else {
    int i2 = idx - 4 * 36864;
    if (i2 < NH * 4096) {
      int h = i2 >> 12;
      int ij = i2 & 4095;
      rb[i2] = btab[ridx[ij] * NH + h];      // rb[h][i][j]
    }
  }
}

// ---------------- fused window attention, 4 windows/block pipelined ----------------
__global__ __launch_bounds__(512, 4)
void wattn_kernel(const float* __restrict__ qg, const float* __restrict__ kg,
                  const float* __restrict__ vg, const float* __restrict__ maskg,
                  const float* __restrict__ bq, const float* __restrict__ bk,
                  const float* __restrict__ bv, const float* __restrict__ bp,
                  const u16* __restrict__ WT, const float* __restrict__ rb,
                  float* __restrict__ xout, float* __restrict__ attn_out) {
  __shared__ __align__(16) char smem[81920];   // 3x24KB rotating + 8KB P scratch
  const int tid  = threadIdx.x;
  const int wave = tid >> 6;
  const int lane = tid & 63;
  const int l15  = lane & 15;
  const int lhi  = lane >> 4;
  char* sP = smem + 73728 + wave * 1024;
  const float scale = 0.17677669529663687f;   // 32^-0.5
  const int b0 = blockIdx.x * WPB;

  // per-thread staging LDS byte offsets (6 x float4-worth of bf16)
  int stoff[6];
  #pragma unroll
  for (int it = 0; it < 6; ++it) {
    int fi  = it * 512 + tid;
    int row = fi / 48;
    stoff[it] = row * ROWB + swz(row, (fi - row * 48) * 8);
  }

  char* bQ = smem;
  char* bK = smem + 24576;
  char* bV = smem + 49152;

  // ---- initial stage: window b0 q,k,v -> bf16 LDS ----
  {
    const size_t base = (size_t)b0 * NTOK * CEMB;
    #pragma unroll
    for (int m = 0; m < 3; ++m) {
      const float* src = (m == 0 ? qg : m == 1 ? kg : vg) + base;
      char* dst = (m == 0 ? bQ : m == 1 ? bK : bV);
      #pragma unroll
      for (int it = 0; it < 6; ++it) {
        const float4 v4 = reinterpret_cast<const float4*>(src)[it * 512 + tid];
        u16x4 p;
        p.x = f2b(v4.x); p.y = f2b(v4.y); p.z = f2b(v4.z); p.w = f2b(v4.w);
        *reinterpret_cast<u16x4*>(dst + stoff[it]) = p;
      }
    }
  }
  __syncthreads();

  float4 rq[6], rk[6], rv[6];
  u16x4  cq[6], ck[6];

  #pragma unroll 1
  for (int w = 0; w < WPB; ++w) {
    const int b = b0 + w;
    const bool more = (w + 1 < WPB);
    const size_t nbase = (size_t)(b + 1) * NTOK * CEMB;

    // issue next-window q,k loads (hidden under proj + attn compute)
    if (more) {
      #pragma unroll
      for (int it = 0; it < 6; ++it)
        rq[it] = reinterpret_cast<const float4*>(qg + nbase)[it * 512 + tid];
      #pragma unroll
      for (int it = 0; it < 6; ++it)
        rk[it] = reinterpret_cast<const float4*>(kg + nbase)[it * 512 + tid];
    }

    // ---- Phase 2: QKV projections. 36 col-strips (3 matrices x 12 ct) ----
    f32x4 accv[5][4];
    #pragma unroll
    for (int si = 0; si < 5; ++si) {
      int strip = wave + si * 8;
      if (strip < 36) {
        int m  = strip / 12;
        int ct = strip - m * 12;
        const char* Xs = (m == 0) ? bQ : (m == 1) ? bK : bV;
        const u16* Wt = WT + m * 36864 + (ct * 16 + l15) * CEMB + lhi * 8;
        f32x4 z = {0.f, 0.f, 0.f, 0.f};
        #pragma unroll
        for (int rt = 0; rt < 4; ++rt) accv[si][rt] = z;
        #pragma unroll
        for (int ks = 0; ks < 6; ++ks) {
          bf16x8 bw = *reinterpret_cast<const bf16x8*>(Wt + ks * 32);
          #pragma unroll
          for (int rt = 0; rt < 4; ++rt) {
            int row = rt * 16 + l15;
            bf16x8 ax = *reinterpret_cast<const bf16x8*>(Xs + row * ROWB + swz(row, ks * 64 + lhi * 16));
            accv[si][rt] = __builtin_amdgcn_mfma_f32_16x16x32_bf16(ax, bw, accv[si][rt], 0, 0, 0);
          }
        }
      }
    }
    __syncthreads();   // staged reads done

    #pragma unroll
    for (int si = 0; si < 5; ++si) {
      int strip = wave + si * 8;
      if (strip < 36) {
        int m  = strip / 12;
        int ct = strip - m * 12;
        int n  = ct * 16 + l15;
        float bval = ((m == 0) ? bq : (m == 1) ? bk : bv)[n];
        if (m == 0) {
          #pragma unroll
          for (int rt = 0; rt < 4; ++rt)
            #pragma unroll
            for (int r = 0; r < 4; ++r) {
              int row = rt * 16 + lhi * 4 + r;
              *reinterpret_cast<u16*>(bQ + row * ROWB + swz(row, n * 2)) = f2b((accv[si][rt][r] + bval) * scale);
            }
        } else if (m == 1) {
          #pragma unroll
          for (int rt = 0; rt < 4; ++rt)
            #pragma unroll
            for (int r = 0; r < 4; ++r) {
              int row = rt * 16 + lhi * 4 + r;
              *reinterpret_cast<u16*>(bK + row * ROWB + swz(row, n * 2)) = f2b(accv[si][rt][r] + bval);
            }
        } else {   // vhT[chan n][token]
          #pragma unroll
          for (int rt = 0; rt < 4; ++rt) {
            int t0 = rt * 16 + lhi * 4;
            u16x4 pk;
            #pragma unroll
            for (int r = 0; r < 4; ++r) pk[r] = f2b(accv[si][rt][r] + bval);
            *reinterpret_cast<u16x4*>(bV + n * VROWB + swz(n, t0 * 2)) = pk;
          }
        }
      }
    }
    // compress next-window q,k to bf16 in-register (frees raw fp32 regs)
    if (more) {
      #pragma unroll
      for (int it = 0; it < 6; ++it) {
        cq[it].x = f2b(rq[it].x); cq[it].y = f2b(rq[it].y);
        cq[it].z = f2b(rq[it].z); cq[it].w = f2b(rq[it].w);
        ck[it].x = f2b(rk[it].x); ck[it].y = f2b(rk[it].y);
        ck[it].z = f2b(rk[it].z); ck[it].w = f2b(rk[it].w);
      }
    }
    __syncthreads();   // qh/kh/vhT ready

    // issue next-window v loads (hidden under attention)
    if (more) {
      #pragma unroll
      for (int it = 0; it < 6; ++it)
        rv[it] = reinterpret_cast<const float4*>(vg + nbase)[it * 512 + tid];
    }

    // ---- Phase 3: per (head, row-tile) unit ----
    const float* maskw = maskg + (size_t)(b & 1023) * 4096;
    #pragma unroll
    for (int ui = 0; ui < 3; ++ui) {
      int u  = wave + ui * 8;        // 0..23
      int h  = u >> 2;
      int rt = u & 3;
      int irow = rt * 16 + lhi * 4;

      const float* rbp = rb + h * 4096 + irow * 64 + l15;
      const float* mkp = maskw + irow * 64 + l15;
      float rbv[4][4], mkv[4][4];
      #pragma unroll
      for (int ct = 0; ct < 4; ++ct)
        #pragma unroll
        for (int r = 0; r < 4; ++r) {
          rbv[ct][r] = rbp[r * 64 + ct * 16];
          mkv[ct][r] = mkp[r * 64 + ct * 16];
        }

      int qrow = rt * 16 + l15;
      bf16x8 aq = *reinterpret_cast<const bf16x8*>(bQ + qrow * ROWB + swz(qrow, h * 64 + lhi * 16));
      f32x4 sv[4];
      #pragma unroll
      for (int ct = 0; ct < 4; ++ct) {
        int krow = ct * 16 + l15;
        bf16x8 bkf = *reinterpret_cast<const bf16x8*>(bK + krow * ROWB + swz(krow, h * 64 + lhi * 16));
        f32x4 z = {0.f, 0.f, 0.f, 0.f};
        sv[ct] = __builtin_amdgcn_mfma_f32_16x16x32_bf16(aq, bkf, z, 0, 0, 0);
      }

      float lg[4][4];
      #pragma unroll
      for (int ct = 0; ct < 4; ++ct)
        #pragma unroll
        for (int r = 0; r < 4; ++r)
          lg[ct][r] = sv[ct][r] + rbv[ct][r] + mkv[ct][r];

      float pr[4][4];
      #pragma unroll
      for (int r = 0; r < 4; ++r) {
        float mx = fmaxf(fmaxf(lg[0][r], lg[1][r]), fmaxf(lg[2][r], lg[3][r]));
        mx = fmaxf(mx, __shfl_xor(mx, 1));
        mx = fmaxf(mx, __shfl_xor(mx, 2));
        mx = fmaxf(mx, __shfl_xor(mx, 4));
        mx = fmaxf(mx, __shfl_xor(mx, 8));
        float e0 = __expf(lg[0][r] - mx), e1 = __expf(lg[1][r] - mx);
        float e2 = __expf(lg[2][r] - mx), e3 = __expf(lg[3][r] - mx);
        float sum = e0 + e1 + e2 + e3;
        sum += __shfl_xor(sum, 1);
        sum += __shfl_xor(sum, 2);
        sum += __shfl_xor(sum, 4);
        sum += __shfl_xor(sum, 8);
        float inv = 1.0f / sum;
        pr[0][r] = e0 * inv; pr[1][r] = e1 * inv; pr[2][r] = e2 * inv; pr[3][r] = e3 * inv;
      }

      float* ap = attn_out + (((size_t)b * NH + h) * NTOK + irow) * NTOK;
      #pragma unroll
      for (int ct = 0; ct < 4; ++ct)
        #pragma unroll
        for (int r = 0; r < 4; ++r)
          ap[r * 64 + ct * 16 + l15] = pr[ct][r];

      // PV through lane-ordered per-wave P scratch, two K=32 halves
      f32x4 xa[2];
      { f32x4 z = {0.f, 0.f, 0.f, 0.f}; xa[0] = z; xa[1] = z; }
      #pragma unroll
      for (int ks = 0; ks < 2; ++ks) {
        #pragma unroll
        for (int c = 0; c < 2; ++c)
          #pragma unroll
          for (int r = 0; r < 4; ++r) {
            int col  = c * 16 + l15;
            int kgp  = col >> 3;
            int j    = col & 7;
            int prow = lhi * 4 + r;
            *reinterpret_cast<u16*>(sP + ((kgp * 16 + prow) * 8 + j) * 2) = f2b(pr[ks * 2 + c][r]);
          }
        bf16x8 apf = *reinterpret_cast<const bf16x8*>(sP + lane * 16);
        #pragma unroll
        for (int ctv = 0; ctv < 2; ++ctv) {
          int vrow = h * 32 + ctv * 16 + l15;
          bf16x8 bvf = *reinterpret_cast<const bf16x8*>(bV + vrow * VROWB + swz(vrow, ks * 64 + lhi * 16));
          xa[ctv] = __builtin_amdgcn_mfma_f32_16x16x32_bf16(apf, bvf, xa[ctv], 0, 0, 0);
        }
      }

      // X in place over qh
      #pragma unroll
      for (int ctv = 0; ctv < 2; ++ctv)
        #pragma unroll
        for (int r = 0; r < 4; ++r) {
          int xrow = rt * 16 + lhi * 4 + r;
          int xcol = h * 32 + ctv * 16 + l15;
          *reinterpret_cast<u16*>(bQ + xrow * ROWB + swz(xrow, xcol * 2)) = f2b(xa[ctv][r]);
        }
    }
    __syncthreads();   // X complete; bK/bV dead

    // stage next-window q,k into freed buffers (overlaps phase 4)
    if (more) {
      #pragma unroll
      for (int it = 0; it < 6; ++it) *reinterpret_cast<u16x4*>(bK + stoff[it]) = cq[it];
      #pragma unroll
      for (int it = 0; it < 6; ++it) *reinterpret_cast<u16x4*>(bV + stoff[it]) = ck[it];
    }

    // ---- Phase 4: out = x @ Wp + bp ----
    #pragma unroll
    for (int ui = 0; ui < 3; ++ui) {
      int u2 = wave + ui * 8;
      int ct = u2 % 12;
      int rh = u2 / 12;
      const u16* Wt = WT + 3 * 36864 + (ct * 16 + l15) * CEMB + lhi * 8;
      f32x4 oa[2];
      { f32x4 z = {0.f, 0.f, 0.f, 0.f}; oa[0] = z; oa[1] = z; }
      #pragma unroll
      for (int ks = 0; ks < 6; ++ks) {
        bf16x8 bw = *reinterpret_cast<const bf16x8*>(Wt + ks * 32);
        #pragma unroll
        for (int rr = 0; rr < 2; ++rr) {
          int xrow = rh * 32 + rr * 16 + l15;
          bf16x8 ax = *reinterpret_cast<const bf16x8*>(bQ + xrow * ROWB + swz(xrow, ks * 64 + lhi * 16));
          oa[rr] = __builtin_amdgcn_mfma_f32_16x16x32_bf16(ax, bw, oa[rr], 0, 0, 0);
        }
      }
      float bias = bp[ct * 16 + l15];
      #pragma unroll
      for (int rr = 0; rr < 2; ++rr)
        #pragma unroll
        for (int r = 0; r < 4; ++r)
          xout[((size_t)b * NTOK + rh * 32 + rr * 16 + lhi * 4 + r) * CEMB + ct * 16 + l15] = oa[rr][r] + bias;
    }
    __syncthreads();   // bQ (X) reads done

    if (more) {
      // stage next-window v into freed bQ
      #pragma unroll
      for (int it = 0; it < 6; ++it) {
        u16x4 cv;
        cv.x = f2b(rv[it].x); cv.y = f2b(rv[it].y);
        cv.z = f2b(rv[it].z); cv.w = f2b(rv[it].w);
        *reinterpret_cast<u16x4*>(bQ + stoff[it]) = cv;
      }
    }
    // rotate buffer roles: q <- old k-slot, k <- old v-slot, v <- old q-slot
    char* t = bQ; bQ = bK; bK = bV; bV = t;
    if (more) __syncthreads();   // staged v visible before next proj
  }
}

extern "C" void kernel_launch(void* const* d_in, const int* in_sizes, int n_in,
                              void* d_out, int out_size, void* d_ws, size_t ws_size,
                              hipStream_t stream) {
  const float* q    = (const float*)d_in[0];
  const float* k    = (const float*)d_in[1];
  const float* v    = (const float*)d_in[2];
  const float* mask = (const float*)d_in[3];
  const float* Wq   = (const float*)d_in[4];
  const float* bq   = (const float*)d_in[5];
  const float* Wk   = (const float*)d_in[6];
  const float* bk   = (const float*)d_in[7];
  const float* Wv   = (const float*)d_in[8];
  const float* bv   = (const float*)d_in[9];
  const float* Wp   = (const float*)d_in[10];
  const float* bp   = (const float*)d_in[11];
  const float* btab = (const float*)d_in[12];
  const int*   ridx = (const int*)d_in[13];

  u16*   WT = (u16*)d_ws;                               // 4 * 36864 bf16
  float* rb = (float*)((char*)d_ws + 4 * 36864 * 2);    // 6*64*64 fp32

  float* xout = (float*)d_out;
  float* attn = xout + (size_t)2048 * NTOK * CEMB;

  prep_kernel<<<672, 256, 0, stream>>>(Wq, Wk, Wv, Wp, btab, ridx, WT, rb);
  wattn_kernel<<<512, 512, 0, stream>>>(q, k, v, mask, bq, bk, bv, bp, WT, rb, xout, attn);
}

// Round 4
// 760.880 us; speedup vs baseline: 1.2234x; 1.2234x over previous
//
#include <hip/hip_runtime.h>
#include <hip/hip_bf16.h>

typedef __attribute__((ext_vector_type(8))) short   bf16x8;
typedef __attribute__((ext_vector_type(4))) float   f32x4;
typedef unsigned short u16;

#define NTOK 64
#define CEMB 192
#define NH   6
#define ROWB 384   // row bytes for [64][192] bf16 LDS tiles

__device__ __forceinline__ u16 f2b(float f) {
  unsigned u = __float_as_uint(f);
  unsigned r = (u + 0x7fffu + ((u >> 16) & 1u)) >> 16;  // RNE
  return (u16)r;
}

// hardware packed f32->bf16 (lo -> bits[15:0], hi -> bits[31:16])
__device__ __forceinline__ unsigned cvtpk(float lo, float hi) {
  unsigned r;
  asm("v_cvt_pk_bf16_f32 %0, %1, %2" : "=v"(r) : "v"(lo), "v"(hi));
  return r;
}

__device__ __forceinline__ int swz(int row, int colbyte) {
  return colbyte ^ ((((row >> 3) ^ row) & 7) << 4);
}

// ---------------- prep: pack W^T (bf16) + gather rel_bias ----------------
__global__ void prep_kernel(const float* __restrict__ Wq, const float* __restrict__ Wk,
                            const float* __restrict__ Wv, const float* __restrict__ Wp,
                            const float* __restrict__ btab, const int* __restrict__ ridx,
                            u16* __restrict__ WT, float* __restrict__ rb) {
  int idx = blockIdx.x * 256 + threadIdx.x;
  if (idx < 4 * 36864) {
    int m = idx / 36864;
    int e = idx - m * 36864;
    int n = e / CEMB;
    int k = e - n * CEMB;
    const float* W = (m == 0) ? Wq : (m == 1) ? Wk : (m == 2) ? Wv : Wp;
    WT[idx] = f2b(W[k * CEMB + n]);          // WT[m][n][k] = W[k][n]
  } else {
    int i2 = idx - 4 * 36864;
    if (i2 < NH * 4096) {
      int h = i2 >> 12;
      int ij = i2 & 4095;
      rb[i2] = btab[ridx[ij] * NH + h];      // rb[h][i][j]
    }
  }
}

// ---------------- K1: QKV projection, one (matrix, window) per block ----------------
// Writes bf16 proj data into d_out regions that K2 overwrites only later:
//   attnU = attn[b] h4..5 slot (32KB): qh01@0, kh01@4096, qh23@8192, kh23@12288 (u16 idx)
//   xU    = x[b] slot (48KB):          qh45@0, kh45@4096, vhT@8192 (12288 u16)
__global__ __launch_bounds__(256, 6)
void proj_kernel(const float* __restrict__ qg, const float* __restrict__ kg,
                 const float* __restrict__ vg,
                 const float* __restrict__ bq, const float* __restrict__ bk,
                 const float* __restrict__ bv,
                 const u16* __restrict__ WT,
                 float* __restrict__ xout, float* __restrict__ attn_out) {
  __shared__ __align__(16) char sT[24576];
  const int tid  = threadIdx.x;
  const int wave = tid >> 6;
  const int lane = tid & 63;
  const int l15  = lane & 15;
  const int lhi  = lane >> 4;
  const int m = blockIdx.x / 2048;        // 0=q 1=k 2=v
  const int b = blockIdx.x - m * 2048;

  const float* src  = (m == 0 ? qg : m == 1 ? kg : vg) + (size_t)b * NTOK * CEMB;
  const float* bias = (m == 0 ? bq : m == 1 ? bk : bv);

  // stage raw tile -> bf16 LDS (swizzled), hw cvt_pk
  #pragma unroll
  for (int it = 0; it < 12; ++it) {
    int fi  = it * 256 + tid;              // 0..3071 float4s
    int row = fi / 48;
    int ce  = (fi - row * 48) * 4;
    const float4 v4 = reinterpret_cast<const float4*>(src)[fi];
    uint2 w;
    w.x = cvtpk(v4.x, v4.y);
    w.y = cvtpk(v4.z, v4.w);
    *reinterpret_cast<uint2*>(sT + row * ROWB + swz(row, ce * 2)) = w;
  }
  __syncthreads();

  u16* attnU = (u16*)(attn_out + (size_t)b * 24576 + 16384);
  u16* xU    = (u16*)(xout + (size_t)b * 12288);
  const float scale = (m == 0) ? 0.17677669529663687f : 1.0f;

  #pragma unroll
  for (int si = 0; si < 3; ++si) {
    int ct = wave + si * 4;                // col strip 0..11
    const u16* Wt = WT + m * 36864 + (ct * 16 + l15) * CEMB + lhi * 8;
    f32x4 acc[4];
    { f32x4 z = {0.f, 0.f, 0.f, 0.f}; acc[0]=z; acc[1]=z; acc[2]=z; acc[3]=z; }
    #pragma unroll
    for (int ks = 0; ks < 6; ++ks) {
      bf16x8 bw = *reinterpret_cast<const bf16x8*>(Wt + ks * 32);
      #pragma unroll
      for (int rt = 0; rt < 4; ++rt) {
        int row = rt * 16 + l15;
        bf16x8 ax = *reinterpret_cast<const bf16x8*>(sT + row * ROWB + swz(row, ks * 64 + lhi * 16));
        acc[rt] = __builtin_amdgcn_mfma_f32_16x16x32_bf16(ax, bw, acc[rt], 0, 0, 0);
      }
    }
    int c = ct * 16 + l15;
    float bval = bias[c];
    if (m == 2) {
      // vhT[c][token]
      #pragma unroll
      for (int rt = 0; rt < 4; ++rt) {
        int t0 = rt * 16 + lhi * 4;
        uint2 w;
        w.x = cvtpk(acc[rt][0] + bval, acc[rt][1] + bval);
        w.y = cvtpk(acc[rt][2] + bval, acc[rt][3] + bval);
        *reinterpret_cast<uint2*>(xU + 8192 + c * 64 + t0) = w;
      }
    } else {
      int p = c >> 6;                       // head-pair 0..2
      u16* base = (p == 2 ? xU : attnU + p * 8192) + m * 4096 + (c & 63);
      #pragma unroll
      for (int rt = 0; rt < 4; ++rt)
        #pragma unroll
        for (int r = 0; r < 4; ++r)
          base[(rt * 16 + lhi * 4 + r) * 64] = f2b((acc[rt][r] + bval) * scale);
    }
  }
}

// ---------------- K2: attention + out-proj, one window per block ----------------
__global__ __launch_bounds__(512, 6)
void attn_kernel(const float* __restrict__ maskg, const float* __restrict__ bp,
                 const u16* __restrict__ WT, const float* __restrict__ rb,
                 float* __restrict__ xout, float* __restrict__ attn_out) {
  __shared__ __align__(16) char smem[32768];   // sX [64][192] bf16 @0, sP 8x1KB @24576
  char* sX = smem;
  const int tid  = threadIdx.x;
  const int wave = tid >> 6;
  const int lane = tid & 63;
  const int l15  = lane & 15;
  const int lhi  = lane >> 4;
  char* sP = smem + 24576 + wave * 1024;
  const int b = blockIdx.x;

  const u16* attnU = (const u16*)(attn_out + (size_t)b * 24576 + 16384);
  const u16* xU    = (const u16*)(xout + (size_t)b * 12288);
  const float* maskw = maskg + (size_t)(b & 1023) * 4096;

  const int rt   = wave & 3;
  const int hq   = wave >> 2;               // 0/1: head parity
  const int irow = rt * 16 + lhi * 4;

  #pragma unroll
  for (int ui = 0; ui < 3; ++ui) {
    int h = 2 * ui + hq;
    int p = h >> 1;                         // == ui
    const u16* region = (p == 2) ? xU : attnU + p * 8192;
    int cl = (h & 1) * 32 + lhi * 8;        // chan-local within 64-chan pair region

    // prefetch bias + mask
    const float* rbp = rb + h * 4096 + irow * 64 + l15;
    const float* mkp = maskw + irow * 64 + l15;
    float rbv[4][4], mkv[4][4];
    #pragma unroll
    for (int ct = 0; ct < 4; ++ct)
      #pragma unroll
      for (int r = 0; r < 4; ++r) {
        rbv[ct][r] = rbp[r * 64 + ct * 16];
        mkv[ct][r] = mkp[r * 64 + ct * 16];
      }

    // S = qh @ kh^T  (K=32), frags straight from global (L2)
    bf16x8 aq = *reinterpret_cast<const bf16x8*>(region + (rt * 16 + l15) * 64 + cl);
    f32x4 sv[4];
    #pragma unroll
    for (int ct = 0; ct < 4; ++ct) {
      bf16x8 bkf = *reinterpret_cast<const bf16x8*>(region + 4096 + (ct * 16 + l15) * 64 + cl);
      f32x4 z = {0.f, 0.f, 0.f, 0.f};
      sv[ct] = __builtin_amdgcn_mfma_f32_16x16x32_bf16(aq, bkf, z, 0, 0, 0);
    }

    float lg[4][4];
    #pragma unroll
    for (int ct = 0; ct < 4; ++ct)
      #pragma unroll
      for (int r = 0; r < 4; ++r)
        lg[ct][r] = sv[ct][r] + rbv[ct][r] + mkv[ct][r];

    float pr[4][4];
    #pragma unroll
    for (int r = 0; r < 4; ++r) {
      float mx = fmaxf(fmaxf(lg[0][r], lg[1][r]), fmaxf(lg[2][r], lg[3][r]));
      mx = fmaxf(mx, __shfl_xor(mx, 1));
      mx = fmaxf(mx, __shfl_xor(mx, 2));
      mx = fmaxf(mx, __shfl_xor(mx, 4));
      mx = fmaxf(mx, __shfl_xor(mx, 8));
      float e0 = __expf(lg[0][r] - mx), e1 = __expf(lg[1][r] - mx);
      float e2 = __expf(lg[2][r] - mx), e3 = __expf(lg[3][r] - mx);
      float sum = e0 + e1 + e2 + e3;
      sum += __shfl_xor(sum, 1);
      sum += __shfl_xor(sum, 2);
      sum += __shfl_xor(sum, 4);
      sum += __shfl_xor(sum, 8);
      float inv = 1.0f / sum;
      pr[0][r] = e0 * inv; pr[1][r] = e1 * inv; pr[2][r] = e2 * inv; pr[3][r] = e3 * inv;
    }

    // attn probs to global. Rounds 0/1 write h0-3 regions (pure output);
    // round 2 writes the h4/5 region, whose qh/kh payload was consumed in
    // rounds 0/1 (barrier below protects).
    float* ap = attn_out + (((size_t)b * NH + h) * NTOK + irow) * NTOK;
    #pragma unroll
    for (int ct = 0; ct < 4; ++ct)
      #pragma unroll
      for (int r = 0; r < 4; ++r)
        ap[r * 64 + ct * 16 + l15] = pr[ct][r];

    // PV through lane-ordered per-wave P scratch; V frags from global vhT
    f32x4 xa[2];
    { f32x4 z = {0.f, 0.f, 0.f, 0.f}; xa[0] = z; xa[1] = z; }
    #pragma unroll
    for (int ks = 0; ks < 2; ++ks) {
      #pragma unroll
      for (int c = 0; c < 2; ++c)
        #pragma unroll
        for (int r = 0; r < 4; ++r) {
          int col  = c * 16 + l15;
          int kgp  = col >> 3;
          int j    = col & 7;
          int prow = lhi * 4 + r;
          *reinterpret_cast<u16*>(sP + ((kgp * 16 + prow) * 8 + j) * 2) = f2b(pr[ks * 2 + c][r]);
        }
      bf16x8 apf = *reinterpret_cast<const bf16x8*>(sP + lane * 16);
      #pragma unroll
      for (int ctv = 0; ctv < 2; ++ctv) {
        int chan = h * 32 + ctv * 16 + l15;
        bf16x8 bvf = *reinterpret_cast<const bf16x8*>(xU + 8192 + chan * 64 + ks * 32 + lhi * 8);
        xa[ctv] = __builtin_amdgcn_mfma_f32_16x16x32_bf16(apf, bvf, xa[ctv], 0, 0, 0);
      }
    }

    // X -> LDS (swizzled)
    #pragma unroll
    for (int ctv = 0; ctv < 2; ++ctv)
      #pragma unroll
      for (int r = 0; r < 4; ++r) {
        int xrow = rt * 16 + lhi * 4 + r;
        int xcol = h * 32 + ctv * 16 + l15;
        *reinterpret_cast<u16*>(sX + xrow * ROWB + swz(xrow, xcol * 2)) = f2b(xa[ctv][r]);
      }

    if (ui == 1) __syncthreads();   // all h0-3 proj reads done before round-2 attn stores
  }
  __syncthreads();   // X complete; all xU proj reads done

  // ---- out = X @ Wp + bp ----
  #pragma unroll
  for (int ui = 0; ui < 3; ++ui) {
    int u2 = wave + ui * 8;
    int ct = u2 % 12;
    int rh = u2 / 12;
    const u16* Wt = WT + 3 * 36864 + (ct * 16 + l15) * CEMB + lhi * 8;
    f32x4 oa[2];
    { f32x4 z = {0.f, 0.f, 0.f, 0.f}; oa[0] = z; oa[1] = z; }
    #pragma unroll
    for (int ks = 0; ks < 6; ++ks) {
      bf16x8 bw = *reinterpret_cast<const bf16x8*>(Wt + ks * 32);
      #pragma unroll
      for (int rr = 0; rr < 2; ++rr) {
        int xrow = rh * 32 + rr * 16 + l15;
        bf16x8 ax = *reinterpret_cast<const bf16x8*>(sX + xrow * ROWB + swz(xrow, ks * 64 + lhi * 16));
        oa[rr] = __builtin_amdgcn_mfma_f32_16x16x32_bf16(ax, bw, oa[rr], 0, 0, 0);
      }
    }
    float bias = bp[ct * 16 + l15];
    #pragma unroll
    for (int rr = 0; rr < 2; ++rr)
      #pragma unroll
      for (int r = 0; r < 4; ++r)
        xout[((size_t)b * NTOK + rh * 32 + rr * 16 + lhi * 4 + r) * CEMB + ct * 16 + l15] = oa[rr][r] + bias;
  }
}

extern "C" void kernel_launch(void* const* d_in, const int* in_sizes, int n_in,
                              void* d_out, int out_size, void* d_ws, size_t ws_size,
                              hipStream_t stream) {
  const float* q    = (const float*)d_in[0];
  const float* k    = (const float*)d_in[1];
  const float* v    = (const float*)d_in[2];
  const float* mask = (const float*)d_in[3];
  const float* Wq   = (const float*)d_in[4];
  const float* bq   = (const float*)d_in[5];
  const float* Wk   = (const float*)d_in[6];
  const float* bk   = (const float*)d_in[7];
  const float* Wv   = (const float*)d_in[8];
  const float* bv   = (const float*)d_in[9];
  const float* Wp   = (const float*)d_in[10];
  const float* bp   = (const float*)d_in[11];
  const float* btab = (const float*)d_in[12];
  const int*   ridx = (const int*)d_in[13];

  u16*   WT = (u16*)d_ws;                               // 4 * 36864 bf16
  float* rb = (float*)((char*)d_ws + 4 * 36864 * 2);    // 6*64*64 fp32

  float* xout = (float*)d_out;
  float* attn = xout + (size_t)2048 * NTOK * CEMB;

  prep_kernel<<<672, 256, 0, stream>>>(Wq, Wk, Wv, Wp, btab, ridx, WT, rb);
  proj_kernel<<<6144, 256, 0, stream>>>(q, k, v, bq, bk, bv, WT, xout, attn);
  attn_kernel<<<2048, 512, 0, stream>>>(mask, bp, WT, rb, xout, attn);
}

// Round 5
// 304.906 us; speedup vs baseline: 3.0530x; 2.4955x over previous
//
#include <hip/hip_runtime.h>
#include <hip/hip_bf16.h>

typedef __attribute__((ext_vector_type(8))) short   bf16x8;
typedef __attribute__((ext_vector_type(4))) float   f32x4;
typedef __attribute__((ext_vector_type(4))) unsigned short u16x4;
typedef unsigned short u16;

#define NTOK 64
#define CEMB 192
#define NH   6
#define ROWB 384   // row bytes for [64][192] bf16 LDS tiles
#define VROWB 128  // row bytes for vhT [192][64] bf16

__device__ __forceinline__ u16 f2b(float f) {
  unsigned u = __float_as_uint(f);
  unsigned r = (u + 0x7fffu + ((u >> 16) & 1u)) >> 16;  // RNE
  return (u16)r;
}

// hardware packed f32->bf16 (lo -> bits[15:0], hi -> bits[31:16])
__device__ __forceinline__ unsigned cvtpk(float lo, float hi) {
  unsigned r;
  asm("v_cvt_pk_bf16_f32 %0, %1, %2" : "=v"(r) : "v"(lo), "v"(hi));
  return r;
}

__device__ __forceinline__ int swz(int row, int colbyte) {
  return colbyte ^ ((((row >> 3) ^ row) & 7) << 4);
}

// ---------------- prep: pack W^T (bf16) + gather rel_bias ----------------
__global__ void prep_kernel(const float* __restrict__ Wq, const float* __restrict__ Wk,
                            const float* __restrict__ Wv, const float* __restrict__ Wp,
                            const float* __restrict__ btab, const int* __restrict__ ridx,
                            u16* __restrict__ WT, float* __restrict__ rb) {
  int idx = blockIdx.x * 256 + threadIdx.x;
  if (idx < 4 * 36864) {
    int m = idx / 36864;
    int e = idx - m * 36864;
    int n = e / CEMB;
    int k = e - n * CEMB;
    const float* W = (m == 0) ? Wq : (m == 1) ? Wk : (m == 2) ? Wv : Wp;
    WT[idx] = f2b(W[k * CEMB + n]);          // WT[m][n][k] = W[k][n]
  } else {
    int i2 = idx - 4 * 36864;
    if (i2 < NH * 4096) {
      int h = i2 >> 12;
      int ij = i2 & 4095;
      rb[i2] = btab[ridx[ij] * NH + h];      // rb[h][i][j]
    }
  }
}

// ---------------- K1: QKV projection, one (matrix, window) per block ----------------
// Linear bf16 outputs (all stores coalesced dwordx4 via LDS transpose):
//   qh [64][192] -> x[b] bytes      0..24576
//   kh [64][192] -> x[b] bytes  24576..49152
//   vhT[192][64] -> attn[b] bytes 65536..90112 (h4/h5 slots)
__global__ __launch_bounds__(256, 4)
void proj_kernel(const float* __restrict__ qg, const float* __restrict__ kg,
                 const float* __restrict__ vg,
                 const float* __restrict__ bq, const float* __restrict__ bk,
                 const float* __restrict__ bv,
                 const u16* __restrict__ WT,
                 float* __restrict__ xout, float* __restrict__ attn_out) {
  __shared__ __align__(16) char sT[24576];
  const int tid  = threadIdx.x;
  const int wave = tid >> 6;
  const int lane = tid & 63;
  const int l15  = lane & 15;
  const int lhi  = lane >> 4;
  const int m = blockIdx.x / 2048;        // 0=q 1=k 2=v
  const int b = blockIdx.x - m * 2048;

  const float* src  = (m == 0 ? qg : m == 1 ? kg : vg) + (size_t)b * NTOK * CEMB;
  const float* bias = (m == 0 ? bq : m == 1 ? bk : bv);

  // stage raw tile -> bf16 LDS (swizzled)
  #pragma unroll
  for (int it = 0; it < 12; ++it) {
    int fi  = it * 256 + tid;              // float4 idx 0..3071
    int row = fi / 48;
    int ce  = (fi - row * 48) * 4;
    const float4 v4 = reinterpret_cast<const float4*>(src)[fi];
    uint2 w;
    w.x = cvtpk(v4.x, v4.y);
    w.y = cvtpk(v4.z, v4.w);
    *reinterpret_cast<uint2*>(sT + row * ROWB + swz(row, ce * 2)) = w;
  }
  __syncthreads();

  // 12 col-strips over 4 waves, 3 per wave; hold all acc (48 VGPR)
  f32x4 acc[3][4];
  #pragma unroll
  for (int si = 0; si < 3; ++si) {
    int ct = wave + si * 4;
    const u16* Wt = WT + m * 36864 + (ct * 16 + l15) * CEMB + lhi * 8;
    #pragma unroll
    for (int rt = 0; rt < 4; ++rt) { f32x4 z = {0.f,0.f,0.f,0.f}; acc[si][rt] = z; }
    #pragma unroll
    for (int ks = 0; ks < 6; ++ks) {
      bf16x8 bw = *reinterpret_cast<const bf16x8*>(Wt + ks * 32);
      #pragma unroll
      for (int rt = 0; rt < 4; ++rt) {
        int row = rt * 16 + l15;
        bf16x8 ax = *reinterpret_cast<const bf16x8*>(sT + row * ROWB + swz(row, ks * 64 + lhi * 16));
        acc[si][rt] = __builtin_amdgcn_mfma_f32_16x16x32_bf16(ax, bw, acc[si][rt], 0, 0, 0);
      }
    }
  }
  __syncthreads();   // staging reads done; sT reusable as output-transpose buffer

  const float scale = (m == 0) ? 0.17677669529663687f : 1.0f;
  #pragma unroll
  for (int si = 0; si < 3; ++si) {
    int ct = wave + si * 4;
    int c  = ct * 16 + l15;
    float bval = bias[c];
    if (m == 2) {
      #pragma unroll
      for (int rt = 0; rt < 4; ++rt) {
        int t0 = rt * 16 + lhi * 4;
        uint2 w;
        w.x = cvtpk(acc[si][rt][0] + bval, acc[si][rt][1] + bval);
        w.y = cvtpk(acc[si][rt][2] + bval, acc[si][rt][3] + bval);
        *reinterpret_cast<uint2*>(sT + c * VROWB + swz(c, t0 * 2)) = w;
      }
    } else {
      #pragma unroll
      for (int rt = 0; rt < 4; ++rt)
        #pragma unroll
        for (int r = 0; r < 4; ++r) {
          int row = rt * 16 + lhi * 4 + r;
          *reinterpret_cast<u16*>(sT + row * ROWB + swz(row, c * 2)) = f2b((acc[si][rt][r] + bval) * scale);
        }
    }
  }
  __syncthreads();

  // coalesced 16B store of the 24KB tile to linear global
  u16* xq = (u16*)(xout + (size_t)b * 12288);
  u16* vt = (u16*)(attn_out + (size_t)b * 24576 + 16384);
  u16* dst = (m == 0) ? xq : (m == 1) ? xq + 12288 : vt;
  #pragma unroll
  for (int c6 = 0; c6 < 6; ++c6) {
    int g = c6 * 256 + tid;                // 16B chunk id 0..1535
    int off;
    if (m == 2) { int row = g >> 3; off = row * VROWB + swz(row, (g & 7) * 16); }
    else        { int row = g / 24; off = row * ROWB  + swz(row, (g % 24) * 16); }
    reinterpret_cast<float4*>(dst)[g] = *reinterpret_cast<const float4*>(sT + off);
  }
}

// ---------------- K2: attention + out-proj, one window per block ----------------
__global__ __launch_bounds__(256, 4)
void attn_kernel(const float* __restrict__ maskg, const float* __restrict__ bp,
                 const u16* __restrict__ WT, const float* __restrict__ rb,
                 float* __restrict__ xout, float* __restrict__ attn_out) {
  __shared__ __align__(16) char smem[28672];   // sX [64][192] bf16 @0, sP 4x1KB @24576
  char* sX = smem;
  const int tid  = threadIdx.x;
  const int wave = tid >> 6;                   // == rt
  const int lane = tid & 63;
  const int l15  = lane & 15;
  const int lhi  = lane >> 4;
  char* sP = smem + 24576 + wave * 1024;
  const int b  = blockIdx.x;
  const int rt = wave;
  const int irow = rt * 16 + lhi * 4;

  const u16* xq = (const u16*)(xout + (size_t)b * 12288);       // qh [64][192]
  const u16* kh = xq + 12288;                                   // kh [64][192]
  const u16* vt = (const u16*)(attn_out + (size_t)b * 24576 + 16384); // vhT [192][64]
  const float* maskw = maskg + (size_t)(b & 1023) * 4096;

  float prD[2][4][4];   // deferred h4/h5 prob stores (their slots hold vhT)

  #pragma unroll
  for (int h = 0; h < NH; ++h) {
    const float* rbp = rb + h * 4096 + irow * 64 + l15;
    const float* mkp = maskw + irow * 64 + l15;
    float rbv[4][4], mkv[4][4];
    #pragma unroll
    for (int ct = 0; ct < 4; ++ct)
      #pragma unroll
      for (int r = 0; r < 4; ++r) {
        rbv[ct][r] = rbp[r * 64 + ct * 16];
        mkv[ct][r] = mkp[r * 64 + ct * 16];
      }

    // S = qh @ kh^T (K=32), frags straight from global (L2/L3)
    bf16x8 aq = *reinterpret_cast<const bf16x8*>(xq + (rt * 16 + l15) * CEMB + h * 32 + lhi * 8);
    f32x4 sv[4];
    #pragma unroll
    for (int ct = 0; ct < 4; ++ct) {
      bf16x8 bkf = *reinterpret_cast<const bf16x8*>(kh + (ct * 16 + l15) * CEMB + h * 32 + lhi * 8);
      f32x4 z = {0.f, 0.f, 0.f, 0.f};
      sv[ct] = __builtin_amdgcn_mfma_f32_16x16x32_bf16(aq, bkf, z, 0, 0, 0);
    }

    float lg[4][4];
    #pragma unroll
    for (int ct = 0; ct < 4; ++ct)
      #pragma unroll
      for (int r = 0; r < 4; ++r)
        lg[ct][r] = sv[ct][r] + rbv[ct][r] + mkv[ct][r];

    float pr[4][4];
    #pragma unroll
    for (int r = 0; r < 4; ++r) {
      float mx = fmaxf(fmaxf(lg[0][r], lg[1][r]), fmaxf(lg[2][r], lg[3][r]));
      mx = fmaxf(mx, __shfl_xor(mx, 1));
      mx = fmaxf(mx, __shfl_xor(mx, 2));
      mx = fmaxf(mx, __shfl_xor(mx, 4));
      mx = fmaxf(mx, __shfl_xor(mx, 8));
      float e0 = __expf(lg[0][r] - mx), e1 = __expf(lg[1][r] - mx);
      float e2 = __expf(lg[2][r] - mx), e3 = __expf(lg[3][r] - mx);
      float sum = e0 + e1 + e2 + e3;
      sum += __shfl_xor(sum, 1);
      sum += __shfl_xor(sum, 2);
      sum += __shfl_xor(sum, 4);
      sum += __shfl_xor(sum, 8);
      float inv = 1.0f / sum;
      pr[0][r] = e0 * inv; pr[1][r] = e1 * inv; pr[2][r] = e2 * inv; pr[3][r] = e3 * inv;
    }

    if (h < 4) {
      float* ap = attn_out + (((size_t)b * NH + h) * NTOK + irow) * NTOK;
      #pragma unroll
      for (int ct = 0; ct < 4; ++ct)
        #pragma unroll
        for (int r = 0; r < 4; ++r)
          ap[r * 64 + ct * 16 + l15] = pr[ct][r];
    } else {
      #pragma unroll
      for (int ct = 0; ct < 4; ++ct)
        #pragma unroll
        for (int r = 0; r < 4; ++r)
          prD[h - 4][ct][r] = pr[ct][r];
    }

    // PV through lane-ordered per-wave P scratch; V frags from global vhT
    f32x4 xa[2];
    { f32x4 z = {0.f, 0.f, 0.f, 0.f}; xa[0] = z; xa[1] = z; }
    #pragma unroll
    for (int ks = 0; ks < 2; ++ks) {
      #pragma unroll
      for (int c = 0; c < 2; ++c)
        #pragma unroll
        for (int r = 0; r < 4; ++r) {
          int col  = c * 16 + l15;
          int kgp  = col >> 3;
          int j    = col & 7;
          int prow = lhi * 4 + r;
          *reinterpret_cast<u16*>(sP + ((kgp * 16 + prow) * 8 + j) * 2) = f2b(pr[ks * 2 + c][r]);
        }
      bf16x8 apf = *reinterpret_cast<const bf16x8*>(sP + lane * 16);
      #pragma unroll
      for (int ctv = 0; ctv < 2; ++ctv) {
        int chan = h * 32 + ctv * 16 + l15;
        bf16x8 bvf = *reinterpret_cast<const bf16x8*>(vt + chan * 64 + ks * 32 + lhi * 8);
        xa[ctv] = __builtin_amdgcn_mfma_f32_16x16x32_bf16(apf, bvf, xa[ctv], 0, 0, 0);
      }
    }

    // X -> LDS (swizzled)
    #pragma unroll
    for (int ctv = 0; ctv < 2; ++ctv)
      #pragma unroll
      for (int r = 0; r < 4; ++r) {
        int xrow = rt * 16 + lhi * 4 + r;
        int xcol = h * 32 + ctv * 16 + l15;
        *reinterpret_cast<u16*>(sX + xrow * ROWB + swz(xrow, xcol * 2)) = f2b(xa[ctv][r]);
      }
  }
  __syncthreads();   // all vhT/qh/kh reads + all X writes complete

  // deferred h4/h5 prob stores (overwrite vhT slots, now dead)
  #pragma unroll
  for (int d = 0; d < 2; ++d) {
    float* ap = attn_out + (((size_t)b * NH + 4 + d) * NTOK + irow) * NTOK;
    #pragma unroll
    for (int ct = 0; ct < 4; ++ct)
      #pragma unroll
      for (int r = 0; r < 4; ++r)
        ap[r * 64 + ct * 16 + l15] = prD[d][ct][r];
  }

  // out = X @ Wp + bp (overwrites qh/kh region of x[b], now dead)
  #pragma unroll
  for (int ui = 0; ui < 6; ++ui) {
    int u2 = wave + ui * 4;
    int ct = u2 % 12;
    int rh = u2 / 12;
    const u16* Wt = WT + 3 * 36864 + (ct * 16 + l15) * CEMB + lhi * 8;
    f32x4 oa[2];
    { f32x4 z = {0.f, 0.f, 0.f, 0.f}; oa[0] = z; oa[1] = z; }
    #pragma unroll
    for (int ks = 0; ks < 6; ++ks) {
      bf16x8 bw = *reinterpret_cast<const bf16x8*>(Wt + ks * 32);
      #pragma unroll
      for (int rr = 0; rr < 2; ++rr) {
        int xrow = rh * 32 + rr * 16 + l15;
        bf16x8 ax = *reinterpret_cast<const bf16x8*>(sX + xrow * ROWB + swz(xrow, ks * 64 + lhi * 16));
        oa[rr] = __builtin_amdgcn_mfma_f32_16x16x32_bf16(ax, bw, oa[rr], 0, 0, 0);
      }
    }
    float bias = bp[ct * 16 + l15];
    #pragma unroll
    for (int rr = 0; rr < 2; ++rr)
      #pragma unroll
      for (int r = 0; r < 4; ++r)
        xout[((size_t)b * NTOK + rh * 32 + rr * 16 + lhi * 4 + r) * CEMB + ct * 16 + l15] = oa[rr][r] + bias;
  }
}

extern "C" void kernel_launch(void* const* d_in, const int* in_sizes, int n_in,
                              void* d_out, int out_size, void* d_ws, size_t ws_size,
                              hipStream_t stream) {
  const float* q    = (const float*)d_in[0];
  const float* k    = (const float*)d_in[1];
  const float* v    = (const float*)d_in[2];
  const float* mask = (const float*)d_in[3];
  const float* Wq   = (const float*)d_in[4];
  const float* bq   = (const float*)d_in[5];
  const float* Wk   = (const float*)d_in[6];
  const float* bk   = (const float*)d_in[7];
  const float* Wv   = (const float*)d_in[8];
  const float* bv   = (const float*)d_in[9];
  const float* Wp   = (const float*)d_in[10];
  const float* bp   = (const float*)d_in[11];
  const float* btab = (const float*)d_in[12];
  const int*   ridx = (const int*)d_in[13];

  u16*   WT = (u16*)d_ws;                               // 4 * 36864 bf16
  float* rb = (float*)((char*)d_ws + 4 * 36864 * 2);    // 6*64*64 fp32

  float* xout = (float*)d_out;
  float* attn = xout + (size_t)2048 * NTOK * CEMB;

  prep_kernel<<<672, 256, 0, stream>>>(Wq, Wk, Wv, Wp, btab, ridx, WT, rb);
  proj_kernel<<<6144, 256, 0, stream>>>(q, k, v, bq, bk, bv, WT, xout, attn);
  attn_kernel<<<2048, 256, 0, stream>>>(mask, bp, WT, rb, xout, attn);
}